// Round 4
// baseline (1061.131 us; speedup 1.0000x reference)
//
#include <hip/hip_runtime.h>
#include <math.h>

#define BB 64
#define SS 256
#define D_IN 400
#define D_RNN 200
#define HID 256
#define G4 1024   // 4*HID

#define NWREG 26   // uint4 weight chunks per gate row held in VGPRs (k < 208)
#define NWLDS 6    // uint4 weight chunks per gate row held in LDS   (k in [208,256))

// workspace layout (float offsets)
#define OFF_WTLIN 0                            // [400][200] f32
#define OFF_WTIH  (OFF_WTLIN + 400*200)        // [2][200][1024] f32
#define OFF_WPACK (OFF_WTIH + 2*200*1024)      // [2][32 chunk][1024 row][8 f16]
#define OFF_X     (OFF_WPACK + 2*1024*256/2)   // [2][64][256][200] f32
#define OFF_GX    (OFF_X + 2*64*256*200)       // [2][64][256][1024] f32

typedef _Float16 half2_t __attribute__((ext_vector_type(2)));

__device__ __forceinline__ half2_t u2h(unsigned u) {
    union { unsigned u; half2_t h; } x; x.u = u; return x.h;
}

__device__ __forceinline__ float dot2acc(unsigned hu, unsigned wu, float acc) {
#if __has_builtin(__builtin_amdgcn_fdot2)
    return __builtin_amdgcn_fdot2(u2h(hu), u2h(wu), acc, false);
#else
    half2_t h = u2h(hu), w = u2h(wu);
    acc = fmaf((float)h.x, (float)w.x, acc);
    acc = fmaf((float)h.y, (float)w.y, acc);
    return acc;
#endif
}

__device__ __forceinline__ float sigm_f(float x) {
    return 1.0f / (1.0f + __expf(-x));
}
__device__ __forceinline__ float tanh_f(float x) {
    return 2.0f / (1.0f + __expf(-2.0f * x)) - 1.0f;
}

// ---------------- transposes / packs ----------------
__global__ void kt_wlin(const float* __restrict__ W, float* __restrict__ Wt) {
    int id = blockIdx.x * 256 + threadIdx.x;
    if (id >= D_RNN * D_IN) return;
    int j = id / D_IN, k = id % D_IN;
    Wt[k * D_RNN + j] = W[id];
}

__global__ void kt_wih(const float* __restrict__ Wl, const float* __restrict__ Wr,
                       float* __restrict__ Wt) {
    int id = blockIdx.x * 256 + threadIdx.x;
    if (id >= 2 * G4 * D_RNN) return;
    int dir = id / (G4 * D_RNN);
    int r = id % (G4 * D_RNN);
    int j = r / D_RNN, k = r % D_RNN;
    const float* src = dir ? Wr : Wl;
    Wt[dir * (D_RNN * G4) + k * G4 + j] = src[r];
}

// Whh f32 [row][k] -> f16 packed chunk-major: wpack[dir][k/8][row][k%8]
// so that k_lstm's per-chunk loads (lane = row%256) are fully coalesced.
__global__ void kt_wpack(const float* __restrict__ Wl, const float* __restrict__ Wr,
                         _Float16* __restrict__ Wp) {
    int id = blockIdx.x * 256 + threadIdx.x;
    if (id >= 2 * G4 * HID) return;
    int dir = id / (G4 * HID);
    int rem = id % (G4 * HID);
    int r = rem / HID, k = rem % HID;
    const float* src = dir ? Wr : Wl;
    Wp[(((size_t)dir * 32 + (k >> 3)) * G4 + r) * 8 + (k & 7)] = (_Float16)src[rem];
}

// ---------------- K1: embeddings + concat + linear + tanh ----------------
__launch_bounds__(512)
__global__ void k_embed_linear(const int* __restrict__ ci, const int* __restrict__ bli,
                               const int* __restrict__ bri, const int* __restrict__ sci,
                               const int* __restrict__ sbli, const int* __restrict__ sbri,
                               const float* __restrict__ ce, const float* __restrict__ be,
                               const float* __restrict__ sce, const float* __restrict__ sbe,
                               const float* __restrict__ Wt, const float* __restrict__ blin,
                               float* __restrict__ xout) {
    __shared__ __align__(16) float vec[16][2][D_IN];
    __shared__ int idx[16][6];
    int tid = threadIdx.x;
    int g0 = blockIdx.x * 16;

    if (tid < 96) {
        int tt = tid / 6, w = tid % 6;
        int g = g0 + tt;
        const int* arr = (w == 0) ? ci : (w == 1) ? sci : (w == 2) ? bli
                         : (w == 3) ? bri : (w == 4) ? sbli : sbri;
        idx[tt][w] = arr[g];
    }
    __syncthreads();

    for (int v = tid; v < 16 * D_IN; v += 512) {
        int tt = v / D_IN, p = v % D_IN;
        float lv, rv;
        if (p < 100)      { float e = ce[idx[tt][0] * 100 + p];          lv = rv = e; }
        else if (p < 200) { float e = sce[idx[tt][1] * 100 + (p - 100)]; lv = rv = e; }
        else if (p < 300) { int q = p - 200;
                            lv = be[idx[tt][2] * 100 + q];
                            rv = be[idx[tt][3] * 100 + q]; }
        else              { int q = p - 300;
                            lv = sbe[idx[tt][4] * 100 + q];
                            rv = sbe[idx[tt][5] * 100 + q]; }
        vec[tt][0][p] = lv;
        vec[tt][1][p] = rv;
    }
    __syncthreads();

    if (tid < 400) {
        int side = tid / 200, j = tid % 200;
        float acc[16];
        #pragma unroll
        for (int t = 0; t < 16; t++) acc[t] = 0.0f;

        for (int k4 = 0; k4 < D_IN / 4; k4++) {
            float w0 = Wt[(4 * k4 + 0) * D_RNN + j];
            float w1 = Wt[(4 * k4 + 1) * D_RNN + j];
            float w2 = Wt[(4 * k4 + 2) * D_RNN + j];
            float w3 = Wt[(4 * k4 + 3) * D_RNN + j];
            #pragma unroll
            for (int t = 0; t < 16; t++) {
                float4 xv = *(const float4*)&vec[t][side][4 * k4];
                acc[t] += xv.x * w0 + xv.y * w1 + xv.z * w2 + xv.w * w3;
            }
        }
        float bias = blin[j];
        #pragma unroll
        for (int t = 0; t < 16; t++) {
            int g = g0 + t;
            int b = g >> 8, s = g & 255;
            xout[((side * BB + b) * SS + s) * D_RNN + j] = tanh_f(acc[t] + bias);
        }
    }
}

// ---------------- K2: gate-x GEMM ----------------
__launch_bounds__(512)
__global__ void k_gatex(const float* __restrict__ x, const float* __restrict__ WtIh,
                        const float* __restrict__ bihl, const float* __restrict__ bhhl,
                        const float* __restrict__ bihr, const float* __restrict__ bhhr,
                        float* __restrict__ gx) {
    __shared__ __align__(16) float xT[D_RNN][36];
    int tid = threadIdx.x;
    int id = blockIdx.x;
    int dir = id >> 9;
    int rem = id & 511;
    int b = rem >> 3;
    int s0 = (rem & 7) * 32;

    const float* xbase = x + ((dir * BB + b) * SS + s0) * D_RNN;
    for (int v = tid; v < 32 * D_RNN; v += 512) {
        int tt = v / D_RNN, k = v % D_RNN;
        xT[k][tt] = xbase[tt * D_RNN + k];
    }
    __syncthreads();

    const float* Wp = WtIh + dir * (D_RNN * G4);
    int j0 = tid, j1 = tid + 512;
    float acc0[32], acc1[32];
    #pragma unroll
    for (int t = 0; t < 32; t++) { acc0[t] = 0.0f; acc1[t] = 0.0f; }

    for (int k = 0; k < D_RNN; k++) {
        float w0 = Wp[k * G4 + j0];
        float w1 = Wp[k * G4 + j1];
        #pragma unroll
        for (int m = 0; m < 8; m++) {
            float4 xv = *(const float4*)&xT[k][4 * m];
            acc0[4 * m + 0] += xv.x * w0;
            acc0[4 * m + 1] += xv.y * w0;
            acc0[4 * m + 2] += xv.z * w0;
            acc0[4 * m + 3] += xv.w * w0;
            acc1[4 * m + 0] += xv.x * w1;
            acc1[4 * m + 1] += xv.y * w1;
            acc1[4 * m + 2] += xv.z * w1;
            acc1[4 * m + 3] += xv.w * w1;
        }
    }

    float bs0, bs1;
    if (dir) { bs0 = bihr[j0] + bhhr[j0]; bs1 = bihr[j1] + bhhr[j1]; }
    else     { bs0 = bihl[j0] + bhhl[j0]; bs1 = bihl[j1] + bhhl[j1]; }

    float* gbase = gx + ((dir * BB + b) * SS + s0) * G4;
    #pragma unroll
    for (int t = 0; t < 32; t++) {
        gbase[t * G4 + j0] = acc0[t] + bs0;
        gbase[t * G4 + j1] = acc1[t] + bs1;
    }
}

// ---------------- K3: LSTM, 256 threads/block, thread t owns all 4 gates of h-col t.
// Whh rows {t,256+t,512+t,768+t}: k<208 in VGPRs (4x26 uint4 = 416 regs),
// k in [208,256) in LDS. h double-buffered in LDS -> ONE barrier per step.
// amdgpu_waves_per_eu(1,1): 1 wave/SIMD => 512-VGPR budget, no spill.
__global__ void
__attribute__((amdgpu_flat_work_group_size(256, 256), amdgpu_waves_per_eu(1, 1)))
k_lstm(const _Float16* __restrict__ wpack, const float* __restrict__ gx,
       float* __restrict__ out) {
    __shared__ __align__(16) uint4 wlds[4 * NWLDS][256];   // 98304 B
    __shared__ __align__(16) _Float16 hbuf[2][HID];        // 1024 B

    int t = threadIdx.x;
    int bid = blockIdx.x;           // 128
    int dir = bid >> 6, b = bid & 63;

    // ---- coalesced weight load from chunk-major pack ----
    const uint4* wp = reinterpret_cast<const uint4*>(wpack) + (size_t)dir * 32 * G4;
    uint4 w0[NWREG], w1[NWREG], w2[NWREG], w3[NWREG];
    #pragma unroll
    for (int i = 0; i < NWREG; i++) {
        w0[i] = wp[i * G4 + 0 * 256 + t];
        w1[i] = wp[i * G4 + 1 * 256 + t];
        w2[i] = wp[i * G4 + 2 * 256 + t];
        w3[i] = wp[i * G4 + 3 * 256 + t];
    }
    #pragma unroll
    for (int j = 0; j < NWLDS; j++) {
        wlds[0 * NWLDS + j][t] = wp[(NWREG + j) * G4 + 0 * 256 + t];
        wlds[1 * NWLDS + j][t] = wp[(NWREG + j) * G4 + 1 * 256 + t];
        wlds[2 * NWLDS + j][t] = wp[(NWREG + j) * G4 + 2 * 256 + t];
        wlds[3 * NWLDS + j][t] = wp[(NWREG + j) * G4 + 3 * 256 + t];
    }

    const float* gxp = gx + (size_t)(dir * BB + b) * SS * G4;
    float* outp = out + (size_t)b * SS * (2 * HID) + dir * HID + t;

    hbuf[0][t] = (_Float16)0.0f;
    float cst = 0.0f;
    __syncthreads();

    int ts = dir ? (SS - 1) : 0;
    int dstep = dir ? -1 : 1;
    const float* gcur = gxp + (size_t)ts * G4;
    float g0 = gcur[t], g1 = gcur[t + 256], g2 = gcur[t + 512], g3 = gcur[t + 768];

    for (int s = 0; s < SS; s++) {
        // prefetch next step's gate-x (hidden under the dots)
        float n0 = 0.f, n1 = 0.f, n2 = 0.f, n3 = 0.f;
        if (s < SS - 1) {
            const float* gn = gxp + (size_t)(ts + dstep) * G4;
            n0 = gn[t]; n1 = gn[t + 256]; n2 = gn[t + 512]; n3 = gn[t + 768];
        }

        const uint4* h4 = reinterpret_cast<const uint4*>(hbuf[s & 1]);
        float a0 = g0, a1 = g1, a2 = g2, a3 = g3;
        #pragma unroll
        for (int i = 0; i < NWREG; i++) {
            uint4 hh = h4[i];
            a0 = dot2acc(hh.x, w0[i].x, a0); a0 = dot2acc(hh.y, w0[i].y, a0);
            a0 = dot2acc(hh.z, w0[i].z, a0); a0 = dot2acc(hh.w, w0[i].w, a0);
            a1 = dot2acc(hh.x, w1[i].x, a1); a1 = dot2acc(hh.y, w1[i].y, a1);
            a1 = dot2acc(hh.z, w1[i].z, a1); a1 = dot2acc(hh.w, w1[i].w, a1);
            a2 = dot2acc(hh.x, w2[i].x, a2); a2 = dot2acc(hh.y, w2[i].y, a2);
            a2 = dot2acc(hh.z, w2[i].z, a2); a2 = dot2acc(hh.w, w2[i].w, a2);
            a3 = dot2acc(hh.x, w3[i].x, a3); a3 = dot2acc(hh.y, w3[i].y, a3);
            a3 = dot2acc(hh.z, w3[i].z, a3); a3 = dot2acc(hh.w, w3[i].w, a3);
        }
        #pragma unroll
        for (int j = 0; j < NWLDS; j++) {
            uint4 hh = h4[NWREG + j];
            uint4 v0 = wlds[0 * NWLDS + j][t];
            uint4 v1 = wlds[1 * NWLDS + j][t];
            uint4 v2 = wlds[2 * NWLDS + j][t];
            uint4 v3 = wlds[3 * NWLDS + j][t];
            a0 = dot2acc(hh.x, v0.x, a0); a0 = dot2acc(hh.y, v0.y, a0);
            a0 = dot2acc(hh.z, v0.z, a0); a0 = dot2acc(hh.w, v0.w, a0);
            a1 = dot2acc(hh.x, v1.x, a1); a1 = dot2acc(hh.y, v1.y, a1);
            a1 = dot2acc(hh.z, v1.z, a1); a1 = dot2acc(hh.w, v1.w, a1);
            a2 = dot2acc(hh.x, v2.x, a2); a2 = dot2acc(hh.y, v2.y, a2);
            a2 = dot2acc(hh.z, v2.z, a2); a2 = dot2acc(hh.w, v2.w, a2);
            a3 = dot2acc(hh.x, v3.x, a3); a3 = dot2acc(hh.y, v3.y, a3);
            a3 = dot2acc(hh.z, v3.z, a3); a3 = dot2acc(hh.w, v3.w, a3);
        }

        float ig = sigm_f(a0);
        float fg = sigm_f(a1);
        float gg = tanh_f(a2);
        float og = sigm_f(a3);
        cst = fg * cst + ig * gg;
        float hv = og * tanh_f(cst);
        outp[(size_t)ts * (2 * HID)] = hv;
        hbuf[(s + 1) & 1][t] = (_Float16)hv;
        __syncthreads();

        g0 = n0; g1 = n1; g2 = n2; g3 = n3;
        ts += dstep;
    }
}

extern "C" void kernel_launch(void* const* d_in, const int* in_sizes, int n_in,
                              void* d_out, int out_size, void* d_ws, size_t ws_size,
                              hipStream_t stream) {
    const int* char_features      = (const int*)d_in[0];
    const int* bichar_left        = (const int*)d_in[1];
    const int* bichar_right       = (const int*)d_in[2];
    const int* static_char        = (const int*)d_in[3];
    const int* static_bichar_left = (const int*)d_in[4];
    const int* static_bichar_right= (const int*)d_in[5];
    const float* char_emb         = (const float*)d_in[6];
    const float* bichar_emb       = (const float*)d_in[7];
    const float* static_char_emb  = (const float*)d_in[8];
    const float* static_bichar_emb= (const float*)d_in[9];
    const float* W_lin            = (const float*)d_in[10];
    const float* b_lin            = (const float*)d_in[11];
    const float* Wih_l            = (const float*)d_in[12];
    const float* Whh_l            = (const float*)d_in[13];
    const float* bih_l            = (const float*)d_in[14];
    const float* bhh_l            = (const float*)d_in[15];
    const float* Wih_r            = (const float*)d_in[16];
    const float* Whh_r            = (const float*)d_in[17];
    const float* bih_r            = (const float*)d_in[18];
    const float* bhh_r            = (const float*)d_in[19];

    float* ws    = (float*)d_ws;
    float* wtlin = ws + OFF_WTLIN;
    float* wtih  = ws + OFF_WTIH;
    _Float16* wpack = (_Float16*)(ws + OFF_WPACK);
    float* xbuf  = ws + OFF_X;
    float* gxbuf = ws + OFF_GX;
    float* out   = (float*)d_out;

    kt_wlin<<<(D_RNN * D_IN + 255) / 256, 256, 0, stream>>>(W_lin, wtlin);
    kt_wih<<<(2 * G4 * D_RNN + 255) / 256, 256, 0, stream>>>(Wih_l, Wih_r, wtih);
    kt_wpack<<<(2 * G4 * HID + 255) / 256, 256, 0, stream>>>(Whh_l, Whh_r, wpack);

    k_embed_linear<<<(BB * SS) / 16, 512, 0, stream>>>(
        char_features, bichar_left, bichar_right, static_char,
        static_bichar_left, static_bichar_right,
        char_emb, bichar_emb, static_char_emb, static_bichar_emb,
        wtlin, b_lin, xbuf);

    k_gatex<<<(2 * BB * SS) / 32, 512, 0, stream>>>(
        xbuf, wtih, bih_l, bhh_l, bih_r, bhh_r, gxbuf);

    k_lstm<<<2 * BB, 256, 0, stream>>>(wpack, gxbuf, out);
}

// Round 5
// 713.359 us; speedup vs baseline: 1.4875x; 1.4875x over previous
//
#include <hip/hip_runtime.h>
#include <math.h>

#define BB 64
#define SS 256
#define D_IN 400
#define D_RNN 200
#define HID 256
#define G4 1024   // 4*HID

// workspace layout (float offsets)
#define OFF_WTLIN 0                            // [400][200] f32
#define OFF_WTIH  (OFF_WTLIN + 400*200)        // [2][100][1024] u32 (f16 pairs)
#define OFF_WPACK (OFF_WTIH + 2*200*1024)      // [2][32 chunk][1024 row][8 f16]
#define OFF_X     (OFF_WPACK + 2*1024*256/2)   // [2][64][256][200] f32
#define OFF_GX    (OFF_X + 2*64*256*200)       // [2][64][256][1024] f32

typedef _Float16 half2_t __attribute__((ext_vector_type(2)));

__device__ __forceinline__ half2_t u2h(unsigned u) {
    union { unsigned u; half2_t h; } x; x.u = u; return x.h;
}

__device__ __forceinline__ float dot2acc(unsigned hu, unsigned wu, float acc) {
#if __has_builtin(__builtin_amdgcn_fdot2)
    return __builtin_amdgcn_fdot2(u2h(hu), u2h(wu), acc, false);
#else
    half2_t h = u2h(hu), w = u2h(wu);
    acc = fmaf((float)h.x, (float)w.x, acc);
    acc = fmaf((float)h.y, (float)w.y, acc);
    return acc;
#endif
}

__device__ __forceinline__ unsigned packf16(float a, float b) {
    union { _Float16 h[2]; unsigned u; } x;
    x.h[0] = (_Float16)a; x.h[1] = (_Float16)b;
    return x.u;
}

__device__ __forceinline__ float sigm_f(float x) {
    return 1.0f / (1.0f + __expf(-x));
}
__device__ __forceinline__ float tanh_f(float x) {
    return 2.0f / (1.0f + __expf(-2.0f * x)) - 1.0f;
}

// ---------------- transposes / packs ----------------
__global__ void kt_wlin(const float* __restrict__ W, float* __restrict__ Wt) {
    int id = blockIdx.x * 256 + threadIdx.x;
    if (id >= D_RNN * D_IN) return;
    int j = id / D_IN, k = id % D_IN;
    Wt[k * D_RNN + j] = W[id];
}

// Wih f32 [1024][200] -> f16-pair pack: Wt16[dir][kk<100][j<1024] = (w[j][2kk], w[j][2kk+1])
__global__ void kt_wih16(const float* __restrict__ Wl, const float* __restrict__ Wr,
                         unsigned* __restrict__ Wt16) {
    int id = blockIdx.x * 256 + threadIdx.x;
    if (id >= 2 * G4 * 100) return;
    int dir = id / (G4 * 100);
    int rem = id % (G4 * 100);
    int j = rem / 100, kk = rem % 100;
    const float* src = dir ? Wr : Wl;
    Wt16[(dir * 100 + kk) * G4 + j] = packf16(src[j * D_RNN + 2 * kk],
                                              src[j * D_RNN + 2 * kk + 1]);
}

// Whh f32 [row][k] -> f16 packed chunk-major: wpack[dir][k/8][row][k%8]
__global__ void kt_wpack(const float* __restrict__ Wl, const float* __restrict__ Wr,
                         _Float16* __restrict__ Wp) {
    int id = blockIdx.x * 256 + threadIdx.x;
    if (id >= 2 * G4 * HID) return;
    int dir = id / (G4 * HID);
    int rem = id % (G4 * HID);
    int r = rem / HID, k = rem % HID;
    const float* src = dir ? Wr : Wl;
    Wp[(((size_t)dir * 32 + (k >> 3)) * G4 + r) * 8 + (k & 7)] = (_Float16)src[rem];
}

// ---------------- K1: embeddings + concat + linear + tanh ----------------
__launch_bounds__(512)
__global__ void k_embed_linear(const int* __restrict__ ci, const int* __restrict__ bli,
                               const int* __restrict__ bri, const int* __restrict__ sci,
                               const int* __restrict__ sbli, const int* __restrict__ sbri,
                               const float* __restrict__ ce, const float* __restrict__ be,
                               const float* __restrict__ sce, const float* __restrict__ sbe,
                               const float* __restrict__ Wt, const float* __restrict__ blin,
                               float* __restrict__ xout) {
    __shared__ __align__(16) float vec[16][2][D_IN];
    __shared__ int idx[16][6];
    int tid = threadIdx.x;
    int g0 = blockIdx.x * 16;

    if (tid < 96) {
        int tt = tid / 6, w = tid % 6;
        int g = g0 + tt;
        const int* arr = (w == 0) ? ci : (w == 1) ? sci : (w == 2) ? bli
                         : (w == 3) ? bri : (w == 4) ? sbli : sbri;
        idx[tt][w] = arr[g];
    }
    __syncthreads();

    for (int v = tid; v < 16 * D_IN; v += 512) {
        int tt = v / D_IN, p = v % D_IN;
        float lv, rv;
        if (p < 100)      { float e = ce[idx[tt][0] * 100 + p];          lv = rv = e; }
        else if (p < 200) { float e = sce[idx[tt][1] * 100 + (p - 100)]; lv = rv = e; }
        else if (p < 300) { int q = p - 200;
                            lv = be[idx[tt][2] * 100 + q];
                            rv = be[idx[tt][3] * 100 + q]; }
        else              { int q = p - 300;
                            lv = sbe[idx[tt][4] * 100 + q];
                            rv = sbe[idx[tt][5] * 100 + q]; }
        vec[tt][0][p] = lv;
        vec[tt][1][p] = rv;
    }
    __syncthreads();

    if (tid < 400) {
        int side = tid / 200, j = tid % 200;
        float acc[16];
        #pragma unroll
        for (int t = 0; t < 16; t++) acc[t] = 0.0f;

        for (int k4 = 0; k4 < D_IN / 4; k4++) {
            float w0 = Wt[(4 * k4 + 0) * D_RNN + j];
            float w1 = Wt[(4 * k4 + 1) * D_RNN + j];
            float w2 = Wt[(4 * k4 + 2) * D_RNN + j];
            float w3 = Wt[(4 * k4 + 3) * D_RNN + j];
            #pragma unroll
            for (int t = 0; t < 16; t++) {
                float4 xv = *(const float4*)&vec[t][side][4 * k4];
                acc[t] += xv.x * w0 + xv.y * w1 + xv.z * w2 + xv.w * w3;
            }
        }
        float bias = blin[j];
        #pragma unroll
        for (int t = 0; t < 16; t++) {
            int g = g0 + t;
            int b = g >> 8, s = g & 255;
            xout[((side * BB + b) * SS + s) * D_RNN + j] = tanh_f(acc[t] + bias);
        }
    }
}

// ---------------- K2: gate-x GEMM via f16 dot2 ----------------
__launch_bounds__(512)
__global__ void k_gatex(const float* __restrict__ x, const unsigned* __restrict__ Wt16,
                        const float* __restrict__ bihl, const float* __restrict__ bhhl,
                        const float* __restrict__ bihr, const float* __restrict__ bhhr,
                        float* __restrict__ gx) {
    __shared__ __align__(16) unsigned xT16[100][40];   // 16000 B
    int tid = threadIdx.x;
    int id = blockIdx.x;
    int dir = id >> 9;
    int rem = id & 511;
    int b = rem >> 3;
    int s0 = (rem & 7) * 32;

    const float2* xb2 = reinterpret_cast<const float2*>(
        x + ((dir * BB + b) * SS + s0) * D_RNN);
    for (int v = tid; v < 32 * 100; v += 512) {
        int tok = v / 100, kk = v % 100;
        float2 p = xb2[tok * 100 + kk];
        xT16[kk][tok] = packf16(p.x, p.y);
    }
    __syncthreads();

    const unsigned* Wp = Wt16 + dir * 100 * G4;
    int j0 = tid, j1 = tid + 512;
    float acc0[32], acc1[32];
    #pragma unroll
    for (int t = 0; t < 32; t++) { acc0[t] = 0.0f; acc1[t] = 0.0f; }

    for (int kk = 0; kk < 100; kk++) {
        unsigned w0 = Wp[kk * G4 + j0];
        unsigned w1 = Wp[kk * G4 + j1];
        #pragma unroll
        for (int m = 0; m < 8; m++) {
            uint4 xx = *(const uint4*)&xT16[kk][4 * m];
            acc0[4 * m + 0] = dot2acc(xx.x, w0, acc0[4 * m + 0]);
            acc0[4 * m + 1] = dot2acc(xx.y, w0, acc0[4 * m + 1]);
            acc0[4 * m + 2] = dot2acc(xx.z, w0, acc0[4 * m + 2]);
            acc0[4 * m + 3] = dot2acc(xx.w, w0, acc0[4 * m + 3]);
            acc1[4 * m + 0] = dot2acc(xx.x, w1, acc1[4 * m + 0]);
            acc1[4 * m + 1] = dot2acc(xx.y, w1, acc1[4 * m + 1]);
            acc1[4 * m + 2] = dot2acc(xx.z, w1, acc1[4 * m + 2]);
            acc1[4 * m + 3] = dot2acc(xx.w, w1, acc1[4 * m + 3]);
        }
    }

    float bs0, bs1;
    if (dir) { bs0 = bihr[j0] + bhhr[j0]; bs1 = bihr[j1] + bhhr[j1]; }
    else     { bs0 = bihl[j0] + bhhl[j0]; bs1 = bihl[j1] + bhhl[j1]; }

    float* gbase = gx + ((dir * BB + b) * SS + s0) * G4;
    #pragma unroll
    for (int t = 0; t < 32; t++) {
        gbase[t * G4 + j0] = acc0[t] + bs0;
        gbase[t * G4 + j1] = acc1[t] + bs1;
    }
}

// ---------------- K3: LSTM. One block per (dir,b), 512 threads.
// Thread (c=t&255, kh=t>>8) computes gate rows {c,c+256,c+512,c+768} over
// K-half [kh*128, kh*128+128). Weights: 12 chunks/row in VGPRs (48 uint4 =
// 192 regs, asm-pinned), 4 chunks/row in LDS. kh=1 writes raw partials;
// kh=0 (owner) adds gx + partials, does nonlins, owns c-state, publishes h.
__global__ void
__attribute__((amdgpu_flat_work_group_size(512, 512), amdgpu_waves_per_eu(2, 2)))
k_lstm(const _Float16* __restrict__ wpack, const float* __restrict__ gx,
       float* __restrict__ out) {
    __shared__ __align__(16) uint4 wlds[16][512];      // 131072 B
    __shared__ __align__(16) float4 exv[256];          // 4096 B
    __shared__ __align__(16) unsigned hbits[2][128];   // 1024 B (256 f16 x2)

    int t = threadIdx.x;
    int c = t & 255, kh = t >> 8;
    int bid = blockIdx.x;           // 128
    int dir = bid >> 6, b = bid & 63;

    // ---- weight load (coalesced, chunk-major pack) ----
    const uint4* wp = reinterpret_cast<const uint4*>(wpack) + (size_t)dir * 32 * G4;
    uint4 wreg[4][12];
    #pragma unroll
    for (int g = 0; g < 4; g++)
        #pragma unroll
        for (int i = 0; i < 12; i++)
            wreg[g][i] = wp[(kh * 16 + i) * G4 + g * 256 + c];
    // pin: forbid sinking/remat of the 192 weight regs
    #pragma unroll
    for (int g = 0; g < 4; g++)
        #pragma unroll
        for (int i = 0; i < 12; i++)
            asm volatile("" : "+v"(wreg[g][i].x), "+v"(wreg[g][i].y),
                              "+v"(wreg[g][i].z), "+v"(wreg[g][i].w));
    #pragma unroll
    for (int g = 0; g < 4; g++)
        #pragma unroll
        for (int i2 = 0; i2 < 4; i2++)
            wlds[g * 4 + i2][t] = wp[(kh * 16 + 12 + i2) * G4 + g * 256 + c];

    const float* gxp = gx + (size_t)(dir * BB + b) * SS * G4;
    float* outp = out + (size_t)b * SS * (2 * HID) + dir * HID + c;

    if (t < 128) { hbits[0][t] = 0u; }
    float cst = 0.0f;
    __syncthreads();

    int ts = dir ? (SS - 1) : 0;
    int dstep = dir ? -1 : 1;
    float gxc[4];
    if (kh == 0) {
        const float* g0p = gxp + (size_t)ts * G4;
        #pragma unroll
        for (int g = 0; g < 4; g++) gxc[g] = g0p[g * 256 + c];
    }

    for (int s = 0; s < SS; s++) {
        // owner prefetches next step's gx (hidden under dots)
        float ngx[4] = {0.f, 0.f, 0.f, 0.f};
        if (kh == 0 && s < SS - 1) {
            const float* gn = gxp + (size_t)(ts + dstep) * G4;
            #pragma unroll
            for (int g = 0; g < 4; g++) ngx[g] = gn[g * 256 + c];
        }

        const uint4* h4 = reinterpret_cast<const uint4*>(hbits[s & 1]);
        float a0, a1, a2, a3;
        if (kh == 0) { a0 = gxc[0]; a1 = gxc[1]; a2 = gxc[2]; a3 = gxc[3]; }
        else         { a0 = a1 = a2 = a3 = 0.0f; }

        #pragma unroll
        for (int i = 0; i < 12; i++) {
            uint4 hh = h4[kh * 16 + i];
            a0 = dot2acc(hh.x, wreg[0][i].x, a0); a0 = dot2acc(hh.y, wreg[0][i].y, a0);
            a0 = dot2acc(hh.z, wreg[0][i].z, a0); a0 = dot2acc(hh.w, wreg[0][i].w, a0);
            a1 = dot2acc(hh.x, wreg[1][i].x, a1); a1 = dot2acc(hh.y, wreg[1][i].y, a1);
            a1 = dot2acc(hh.z, wreg[1][i].z, a1); a1 = dot2acc(hh.w, wreg[1][i].w, a1);
            a2 = dot2acc(hh.x, wreg[2][i].x, a2); a2 = dot2acc(hh.y, wreg[2][i].y, a2);
            a2 = dot2acc(hh.z, wreg[2][i].z, a2); a2 = dot2acc(hh.w, wreg[2][i].w, a2);
            a3 = dot2acc(hh.x, wreg[3][i].x, a3); a3 = dot2acc(hh.y, wreg[3][i].y, a3);
            a3 = dot2acc(hh.z, wreg[3][i].z, a3); a3 = dot2acc(hh.w, wreg[3][i].w, a3);
        }
        #pragma unroll
        for (int i2 = 0; i2 < 4; i2++) {
            uint4 hh = h4[kh * 16 + 12 + i2];
            uint4 v0 = wlds[0 * 4 + i2][t];
            uint4 v1 = wlds[1 * 4 + i2][t];
            uint4 v2 = wlds[2 * 4 + i2][t];
            uint4 v3 = wlds[3 * 4 + i2][t];
            a0 = dot2acc(hh.x, v0.x, a0); a0 = dot2acc(hh.y, v0.y, a0);
            a0 = dot2acc(hh.z, v0.z, a0); a0 = dot2acc(hh.w, v0.w, a0);
            a1 = dot2acc(hh.x, v1.x, a1); a1 = dot2acc(hh.y, v1.y, a1);
            a1 = dot2acc(hh.z, v1.z, a1); a1 = dot2acc(hh.w, v1.w, a1);
            a2 = dot2acc(hh.x, v2.x, a2); a2 = dot2acc(hh.y, v2.y, a2);
            a2 = dot2acc(hh.z, v2.z, a2); a2 = dot2acc(hh.w, v2.w, a2);
            a3 = dot2acc(hh.x, v3.x, a3); a3 = dot2acc(hh.y, v3.y, a3);
            a3 = dot2acc(hh.z, v3.z, a3); a3 = dot2acc(hh.w, v3.w, a3);
        }

        if (kh == 1) exv[c] = make_float4(a0, a1, a2, a3);
        __syncthreads();

        if (kh == 0) {
            float4 p = exv[c];
            float ig = sigm_f(a0 + p.x);
            float fg = sigm_f(a1 + p.y);
            float gg = tanh_f(a2 + p.z);
            float og = sigm_f(a3 + p.w);
            cst = fg * cst + ig * gg;
            float hv = og * tanh_f(cst);
            outp[(size_t)ts * (2 * HID)] = hv;
            reinterpret_cast<unsigned short*>(hbits[(s + 1) & 1])[c] =
                __builtin_bit_cast(unsigned short, (_Float16)hv);
        }
        __syncthreads();

        if (kh == 0) {
            #pragma unroll
            for (int g = 0; g < 4; g++) gxc[g] = ngx[g];
        }
        ts += dstep;
    }
}

extern "C" void kernel_launch(void* const* d_in, const int* in_sizes, int n_in,
                              void* d_out, int out_size, void* d_ws, size_t ws_size,
                              hipStream_t stream) {
    const int* char_features      = (const int*)d_in[0];
    const int* bichar_left        = (const int*)d_in[1];
    const int* bichar_right       = (const int*)d_in[2];
    const int* static_char        = (const int*)d_in[3];
    const int* static_bichar_left = (const int*)d_in[4];
    const int* static_bichar_right= (const int*)d_in[5];
    const float* char_emb         = (const float*)d_in[6];
    const float* bichar_emb       = (const float*)d_in[7];
    const float* static_char_emb  = (const float*)d_in[8];
    const float* static_bichar_emb= (const float*)d_in[9];
    const float* W_lin            = (const float*)d_in[10];
    const float* b_lin            = (const float*)d_in[11];
    const float* Wih_l            = (const float*)d_in[12];
    const float* Whh_l            = (const float*)d_in[13];
    const float* bih_l            = (const float*)d_in[14];
    const float* bhh_l            = (const float*)d_in[15];
    const float* Wih_r            = (const float*)d_in[16];
    const float* Whh_r            = (const float*)d_in[17];
    const float* bih_r            = (const float*)d_in[18];
    const float* bhh_r            = (const float*)d_in[19];

    float* ws    = (float*)d_ws;
    float* wtlin = ws + OFF_WTLIN;
    unsigned* wtih16 = (unsigned*)(ws + OFF_WTIH);
    _Float16* wpack = (_Float16*)(ws + OFF_WPACK);
    float* xbuf  = ws + OFF_X;
    float* gxbuf = ws + OFF_GX;
    float* out   = (float*)d_out;

    kt_wlin<<<(D_RNN * D_IN + 255) / 256, 256, 0, stream>>>(W_lin, wtlin);
    kt_wih16<<<(2 * G4 * 100 + 255) / 256, 256, 0, stream>>>(Wih_l, Wih_r, wtih16);
    kt_wpack<<<(2 * G4 * HID + 255) / 256, 256, 0, stream>>>(Whh_l, Whh_r, wpack);

    k_embed_linear<<<(BB * SS) / 16, 512, 0, stream>>>(
        char_features, bichar_left, bichar_right, static_char,
        static_bichar_left, static_bichar_right,
        char_emb, bichar_emb, static_char_emb, static_bichar_emb,
        wtlin, b_lin, xbuf);

    k_gatex<<<(2 * BB * SS) / 32, 512, 0, stream>>>(
        xbuf, wtih16, bih_l, bhh_l, bih_r, bhh_r, gxbuf);

    k_lstm<<<2 * BB, 512, 0, stream>>>(wpack, gxbuf, out);
}